// Round 2
// baseline (1387.409 us; speedup 1.0000x reference)
//
#include <hip/hip_runtime.h>

#define N_P 100000
#define N_A 50000
#define DD  64
#define E_W 800000
#define E_C 1200000

// ---------------- K1: degree histograms ----------------
__global__ void k_degrees(const int* __restrict__ wsrc, const int* __restrict__ wdst,
                          const int* __restrict__ csrc, const int* __restrict__ cdst,
                          float* __restrict__ deg_a, float* __restrict__ cnt_w,
                          float* __restrict__ deg_p, float* __restrict__ cnt_c) {
    int t = blockIdx.x * blockDim.x + threadIdx.x;
    if (t < E_W) {
        atomicAdd(&deg_a[wsrc[t]], 1.0f);
        atomicAdd(&cnt_w[wdst[t]], 1.0f);
    }
    if (t < E_C) {
        atomicAdd(&deg_p[csrc[t]], 1.0f);
        atomicAdd(&cnt_c[cdst[t]], 1.0f);
    }
}

// ---------------- K2: edge-parallel feature scatter (one wave per edge) ----------------
__global__ __launch_bounds__(256) void k_scatter(
    const float* __restrict__ h_author, const float* __restrict__ h_paper,
    const int* __restrict__ wsrc, const int* __restrict__ wdst,
    const int* __restrict__ csrc, const int* __restrict__ cdst,
    const float* __restrict__ deg_a, const float* __restrict__ deg_p,
    float* __restrict__ rst_w, float* __restrict__ rst_c) {
    const int lane = threadIdx.x & 63;
    const long long wid = (long long)blockIdx.x * (blockDim.x >> 6) + (threadIdx.x >> 6);
    if (wid < E_W) {
        int e = (int)wid;
        int s = wsrc[e], d = wdst[e];
        float sc = rsqrtf(fmaxf(deg_a[s], 1.0f));
        float v = h_author[(size_t)s * DD + lane] * sc;
        atomicAdd(&rst_w[(size_t)d * DD + lane], v);
    } else {
        int e = (int)(wid - E_W);
        if (e < E_C) {
            int s = csrc[e], d = cdst[e];
            float sc = rsqrtf(fmaxf(deg_p[s], 1.0f));
            float v = h_paper[(size_t)s * DD + lane] * sc;
            atomicAdd(&rst_c[(size_t)d * DD + lane], v);
        }
    }
}

// ---------------- K3: per-node GEMV x3 + elu + 2-point hetero softmax ----------------
// One wave per node iteration; lane d computes output feature d.
// W rows live in per-lane VGPRs (reused across all nodes of the wave);
// x rows are wave-uniform -> scalar/broadcast loads.
__global__ __launch_bounds__(256) void k_node(
    const float* __restrict__ h_paper,
    const float* __restrict__ Wl,  const float* __restrict__ bl,
    const float* __restrict__ Wra, const float* __restrict__ bra,
    const float* __restrict__ Wrp, const float* __restrict__ brp,
    const float* __restrict__ rst_w, const float* __restrict__ rst_c,
    const float* __restrict__ cnt_w, const float* __restrict__ cnt_c,
    float* __restrict__ att_w, float* __restrict__ att_c,
    int n_waves) {
    const int lane = threadIdx.x & 63;
    const int wave = blockIdx.x * (blockDim.x >> 6) + (threadIdx.x >> 6);

    float wl[DD], wa[DD], wp[DD];
#pragma unroll
    for (int k = 0; k < DD; ++k) {
        wl[k] = Wl[(size_t)lane * DD + k];
        wa[k] = Wra[(size_t)lane * DD + k];
        wp[k] = Wrp[(size_t)lane * DD + k];
    }
    const float bl_l  = bl[lane];
    const float bra_l = bra[lane];
    const float brp_l = brp[lane];

    for (int node = wave; node < N_P; node += n_waves) {
        const int un = __builtin_amdgcn_readfirstlane(node);
        const float* hrow = h_paper + (size_t)un * DD;
        const float* rw = rst_w + (size_t)un * DD;
        const float* rc = rst_c + (size_t)un * DD;

        float accl = 0.f, accw = 0.f, accp = 0.f;
#pragma unroll
        for (int k = 0; k < DD; ++k) {
            accl = fmaf(hrow[k], wl[k], accl);
            accw = fmaf(rw[k],   wa[k], accw);
            accp = fmaf(rc[k],   wp[k], accp);
        }
        const float cw = cnt_w[un];
        const float cc = cnt_c[un];
        const float sw = rsqrtf(fmaxf(cw, 1.0f));  // in-degree norm (clip >=1)
        const float sc = rsqrtf(fmaxf(cc, 1.0f));

        const float hl  = accl + bl_l;
        const float hrw = accw * sw + bra_l;
        const float hrc = accp * sc + brp_l;
        float xw = hl + hrw, xc = hl + hrc;
        const float eaw = (xw > 0.f) ? xw : expm1f(xw);  // elu
        const float eac = (xc > 0.f) ? xc : expm1f(xc);

        float aw, ac;
        if (cw > 0.f && cc > 0.f) {
            float m  = fmaxf(eaw, eac);
            float ew = __expf(eaw - m);
            float ec = __expf(eac - m);
            float z  = cw * ew + cc * ec;
            aw = ew / z;
            ac = ec / z;
        } else if (cw > 0.f) {
            aw = 1.0f / cw; ac = 0.f;
        } else if (cc > 0.f) {
            ac = 1.0f / cc; aw = 0.f;
        } else {
            aw = 0.f; ac = 0.f;
        }
        att_w[(size_t)un * DD + lane] = aw;
        att_c[(size_t)un * DD + lane] = ac;
    }
}

// ---------------- K4: gather att rows to per-edge output (16B/thread) ----------------
// fp32 rows are 256B = 16 uint4s.
__global__ __launch_bounds__(256) void k_gather(
    const int* __restrict__ wdst, const int* __restrict__ cdst,
    const uint4* __restrict__ attw4, const uint4* __restrict__ attc4,
    uint4* __restrict__ out4) {
    const long long t = (long long)blockIdx.x * blockDim.x + threadIdx.x;
    const long long nw = (long long)E_W * 16;  // uint4s in writes portion
    if (t < nw) {
        int e = (int)(t >> 4), p = (int)(t & 15);
        int d = wdst[e];
        out4[t] = attw4[(size_t)d * 16 + p];
    } else {
        long long u = t - nw;
        if (u < (long long)E_C * 16) {
            int e = (int)(u >> 4), p = (int)(u & 15);
            int d = cdst[e];
            out4[t] = attc4[(size_t)d * 16 + p];
        }
    }
}

extern "C" void kernel_launch(void* const* d_in, const int* in_sizes, int n_in,
                              void* d_out, int out_size, void* d_ws, size_t ws_size,
                              hipStream_t stream) {
    const float* h_paper  = (const float*)d_in[0];
    const float* h_author = (const float*)d_in[1];
    const float* Wl  = (const float*)d_in[2];
    const float* bl  = (const float*)d_in[3];
    const float* Wra = (const float*)d_in[4];
    const float* bra = (const float*)d_in[5];
    const float* Wrp = (const float*)d_in[6];
    const float* brp = (const float*)d_in[7];
    const int* wsrc = (const int*)d_in[8];
    const int* wdst = (const int*)d_in[9];
    const int* csrc = (const int*)d_in[10];
    const int* cdst = (const int*)d_in[11];

    // workspace layout (all fp32)
    float* rst_w = (float*)d_ws;                 // N_P*64
    float* rst_c = rst_w + (size_t)N_P * DD;     // N_P*64
    float* deg_a = rst_c + (size_t)N_P * DD;     // N_A
    float* cnt_w = deg_a + N_A;                  // N_P
    float* deg_p = cnt_w + N_P;                  // N_P
    float* cnt_c = deg_p + N_P;                  // N_P
    float* att_w = cnt_c + N_P;                  // N_P*64
    float* att_c = att_w + (size_t)N_P * DD;     // N_P*64
    size_t zero_bytes = ((size_t)2 * N_P * DD + N_A + 3 * (size_t)N_P) * sizeof(float);

    hipMemsetAsync(d_ws, 0, zero_bytes, stream);

    // K1: degrees
    {
        int threads = 256;
        int blocks = (E_C + threads - 1) / threads;
        k_degrees<<<blocks, threads, 0, stream>>>(wsrc, wdst, csrc, cdst,
                                                  deg_a, cnt_w, deg_p, cnt_c);
    }
    // K2: scatter (one wave per edge)
    {
        long long waves = (long long)E_W + E_C;
        int blocks = (int)((waves + 3) / 4);  // 4 waves per 256-thread block
        k_scatter<<<blocks, 256, 0, stream>>>(h_author, h_paper, wsrc, wdst, csrc, cdst,
                                              deg_a, deg_p, rst_w, rst_c);
    }
    // K3: per-node compute
    {
        int blocks = 512;
        int n_waves = blocks * (256 / 64);
        k_node<<<blocks, 256, 0, stream>>>(h_paper, Wl, bl, Wra, bra, Wrp, brp,
                                           rst_w, rst_c, cnt_w, cnt_c, att_w, att_c, n_waves);
    }
    // K4: gather to output
    {
        long long total = ((long long)E_W + E_C) * 16;
        int blocks = (int)((total + 255) / 256);
        k_gather<<<blocks, 256, 0, stream>>>(wdst, cdst, (const uint4*)att_w,
                                             (const uint4*)att_c, (uint4*)d_out);
    }
}